// Round 6
// baseline (116.315 us; speedup 1.0000x reference)
//
#include <hip/hip_runtime.h>

// Problem constants (from reference): B=128, L=1024, D=2048, f32 in/out.
constexpr int Bc = 128;
constexpr int Lc = 1024;
constexpr int Dc = 2048;

constexpr int THREADS   = 256;
constexpr int VEC       = 4;                   // float4 per thread
constexpr int DCOLS_BLK = THREADS * VEC;       // 1024 columns per block
constexpr int DBLKS     = Dc / DCOLS_BLK;      // 2
constexpr int NL        = 8;                   // row-interleave groups (full residency)

typedef float v4f __attribute__((ext_vector_type(4)));

__global__ __launch_bounds__(THREADS) void avg_pool_var_kernel(
    const float* __restrict__ feat,
    const int*   __restrict__ lengths,
    float*       __restrict__ out)
{
    // blockIdx.x encodes (b, dblk, lc); lc picks rows l ≡ lc (mod NL)
    int bid  = blockIdx.x;
    int lc   = bid % NL;
    int dblk = (bid / NL) % DBLKS;
    int b    = bid / (NL * DBLKS);

    int len = lengths[b];
    int eff = (len > 0) ? len : Lc;

    int col = dblk * DCOLS_BLK + (int)threadIdx.x * VEC;
    const float* p = feat + (size_t)b * Lc * Dc + (size_t)lc * Dc + col;

    float ax = 0.f, ay = 0.f, az = 0.f, aw = 0.f;
    #pragma unroll 8
    for (int l = lc; l < eff; l += NL, p += (size_t)NL * Dc) {
        v4f v = *reinterpret_cast<const v4f*>(p);   // plain cached load (no NT)
        ax += v.x; ay += v.y; az += v.z; aw += v.w;
    }

    float inv = 1.0f / (float)eff;
    float* o = out + (size_t)b * Dc + col;
    atomicAdd(o + 0, ax * inv);
    atomicAdd(o + 1, ay * inv);
    atomicAdd(o + 2, az * inv);
    atomicAdd(o + 3, aw * inv);
}

extern "C" void kernel_launch(void* const* d_in, const int* in_sizes, int n_in,
                              void* d_out, int out_size, void* d_ws, size_t ws_size,
                              hipStream_t stream)
{
    const float* feat    = (const float*)d_in[0];
    const int*   lengths = (const int*)d_in[1];
    float*       out     = (float*)d_out;

    // Harness poisons d_out once and never re-poisons between replays:
    // zero it every call (graph-capture-safe memset node).
    (void)hipMemsetAsync(out, 0, (size_t)out_size * sizeof(float), stream);

    dim3 grid(Bc * DBLKS * NL);
    dim3 block(THREADS);
    avg_pool_var_kernel<<<grid, block, 0, stream>>>(feat, lengths, out);
}

// Round 7
// 99.033 us; speedup vs baseline: 1.1745x; 1.1745x over previous
//
#include <hip/hip_runtime.h>

// Problem constants (from reference): B=128, L=1024, D=2048, f32 in/out.
constexpr int Bc = 128;
constexpr int Lc = 1024;
constexpr int Dc = 2048;

constexpr int THREADS   = 256;
constexpr int VEC       = 4;                   // float4 per thread
constexpr int DCOLS_BLK = THREADS * VEC;       // 1024 columns per block
constexpr int DBLKS     = Dc / DCOLS_BLK;      // 2
constexpr int NL        = 8;                   // row-interleave groups (full residency)

typedef float v4f __attribute__((ext_vector_type(4)));

// ---------------- Stage 1: stream + per-block partial sums (no atomics) ----
__global__ __launch_bounds__(THREADS) void avg_pool_stage1(
    const float* __restrict__ feat,
    const int*   __restrict__ lengths,
    float*       __restrict__ part)    // [Bc][NL][Dc] partial sums
{
    int bid  = blockIdx.x;
    int lc   = bid % NL;
    int dblk = (bid / NL) % DBLKS;
    int b    = bid / (NL * DBLKS);

    int len = lengths[b];
    int eff = (len > 0) ? len : Lc;

    int col = dblk * DCOLS_BLK + (int)threadIdx.x * VEC;
    const float* p = feat + (size_t)b * Lc * Dc + (size_t)lc * Dc + col;

    float ax = 0.f, ay = 0.f, az = 0.f, aw = 0.f;
    #pragma unroll 4
    for (int l = lc; l < eff; l += NL, p += (size_t)NL * Dc) {
        v4f v = __builtin_nontemporal_load(reinterpret_cast<const v4f*>(p));
        ax += v.x; ay += v.y; az += v.z; aw += v.w;
    }

    v4f r; r.x = ax; r.y = ay; r.z = az; r.w = aw;
    float* o = part + ((size_t)b * NL + lc) * Dc + col;
    __builtin_nontemporal_store(r, reinterpret_cast<v4f*>(o));
}

// ---------------- Stage 2: reduce 8 partials, scale, overwrite d_out -------
__global__ __launch_bounds__(THREADS) void avg_pool_stage2(
    const float* __restrict__ part,
    const int*   __restrict__ lengths,
    float*       __restrict__ out)
{
    int g   = blockIdx.x * THREADS + (int)threadIdx.x;  // v4f index
    int b   = g / (Dc / VEC);
    int col = (g % (Dc / VEC)) * VEC;

    int len = lengths[b];
    int eff = (len > 0) ? len : Lc;
    float inv = 1.0f / (float)eff;

    float ax = 0.f, ay = 0.f, az = 0.f, aw = 0.f;
    #pragma unroll
    for (int lc = 0; lc < NL; ++lc) {
        const v4f* p = reinterpret_cast<const v4f*>(
            part + ((size_t)b * NL + lc) * Dc + col);
        v4f v = *p;
        ax += v.x; ay += v.y; az += v.z; aw += v.w;
    }
    v4f r; r.x = ax * inv; r.y = ay * inv; r.z = az * inv; r.w = aw * inv;
    *reinterpret_cast<v4f*>(out + (size_t)b * Dc + col) = r;
}

// ---------------- Fallback: R3 atomic single-kernel path -------------------
__global__ __launch_bounds__(THREADS) void avg_pool_atomic(
    const float* __restrict__ feat,
    const int*   __restrict__ lengths,
    float*       __restrict__ out)
{
    int bid  = blockIdx.x;
    int lc   = bid % NL;
    int dblk = (bid / NL) % DBLKS;
    int b    = bid / (NL * DBLKS);

    int len = lengths[b];
    int eff = (len > 0) ? len : Lc;

    int col = dblk * DCOLS_BLK + (int)threadIdx.x * VEC;
    const float* p = feat + (size_t)b * Lc * Dc + (size_t)lc * Dc + col;

    float ax = 0.f, ay = 0.f, az = 0.f, aw = 0.f;
    #pragma unroll 4
    for (int l = lc; l < eff; l += NL, p += (size_t)NL * Dc) {
        v4f v = __builtin_nontemporal_load(reinterpret_cast<const v4f*>(p));
        ax += v.x; ay += v.y; az += v.z; aw += v.w;
    }

    float inv = 1.0f / (float)eff;
    float* o = out + (size_t)b * Dc + col;
    atomicAdd(o + 0, ax * inv);
    atomicAdd(o + 1, ay * inv);
    atomicAdd(o + 2, az * inv);
    atomicAdd(o + 3, aw * inv);
}

extern "C" void kernel_launch(void* const* d_in, const int* in_sizes, int n_in,
                              void* d_out, int out_size, void* d_ws, size_t ws_size,
                              hipStream_t stream)
{
    const float* feat    = (const float*)d_in[0];
    const int*   lengths = (const int*)d_in[1];
    float*       out     = (float*)d_out;

    const size_t ws_needed = (size_t)Bc * NL * Dc * sizeof(float);  // 8 MB

    if (ws_size >= ws_needed) {
        float* part = (float*)d_ws;
        avg_pool_stage1<<<dim3(Bc * DBLKS * NL), dim3(THREADS), 0, stream>>>(
            feat, lengths, part);
        avg_pool_stage2<<<dim3(Bc * Dc / VEC / THREADS), dim3(THREADS), 0, stream>>>(
            part, lengths, out);
    } else {
        (void)hipMemsetAsync(out, 0, (size_t)out_size * sizeof(float), stream);
        avg_pool_atomic<<<dim3(Bc * DBLKS * NL), dim3(THREADS), 0, stream>>>(
            feat, lengths, out);
    }
}